// Round 4
// baseline (283.796 us; speedup 1.0000x reference)
//
#include <hip/hip_runtime.h>

#define Bn 4
#define Cn 32
#define Hn 320
#define Wn 320
#define NCn 21
#define PADn 3
#define TH 16
#define TW 64
#define HH 22              // TH+6 halo rows
#define HWID 70            // TW+6 halo cols (valid)
#define FW 71              // F row stride in words (odd -> conflict-free)
#define QSTR 76            // Q row stride in bytes (19 words, odd -> conflict-free)
#define C2n 16             // channel pairs
#define HWSZ (Hn*Wn)

typedef _Float16 h2 __attribute__((ext_vector_type(2)));

#define F_WORDS (C2n*HH*FW)                   // 24992 words
#define LDS_Q_OFF (F_WORDS*4)                 // 99968 B
#define LDS_TOTAL (LDS_Q_OFF + NCn*HH*QSTR)   // 99968 + 35112 = 135080 B

__global__ __launch_bounds__(256, 1) void crf_fused(
    const float* __restrict__ Fin, const float* __restrict__ logit,
    const float* __restrict__ weight, const float* __restrict__ compat,
    const float* __restrict__ bias, float* __restrict__ out)
{
  extern __shared__ char smem[];
  uint32_t* fbuf = (uint32_t*)smem;                 // [C2n][HH][FW] half2(ch 2c,2c+1)
  uint8_t*  qbuf = (uint8_t*)(smem + LDS_Q_OFF);    // [NCn][HH][QSTR] fp8 e4m3

  const int bid = blockIdx.x;
  const int b   = bid / 100;
  const int r   = bid % 100;
  const int th  = r / 5, twi = r % 5;
  const int h0  = th * TH, w0 = twi * TW;
  const int tid = threadIdx.x;

  // ---------------- stage F (fp32 global -> fp16 ch-pair words in LDS) -------------
  const float* fb0 = Fin + (size_t)b * Cn * HWSZ;
  for (int idx = tid; idx < C2n * HH * HWID; idx += 256) {
    int lw = idx % HWID;
    int t2 = idx / HWID;
    int lh = t2 % HH;
    int c2 = t2 / HH;
    int gh = h0 - PADn + lh, gw = w0 - PADn + lw;
    uint32_t wd = 0u;
    if ((unsigned)gh < (unsigned)Hn && (unsigned)gw < (unsigned)Wn) {
      const float* p = fb0 + (size_t)(2 * c2) * HWSZ + gh * Wn + gw;
      float a0 = p[0], a1 = p[HWSZ];
      h2 hp; hp[0] = (_Float16)a0; hp[1] = (_Float16)a1;
      wd = __builtin_bit_cast(uint32_t, hp);
    }
    fbuf[(c2 * HH + lh) * FW + lw] = wd;
  }

  // ---------------- stage Q = softmax(logit) as fp8 ---------------------------------
  const float* lg0 = logit + (size_t)b * NCn * HWSZ;
  for (int p = tid; p < HH * HWID; p += 256) {
    int lw = p % HWID, lh = p / HWID;
    int gh = h0 - PADn + lh, gw = w0 - PADn + lw;
    uint8_t* qp = qbuf + lh * QSTR + lw;
    if ((unsigned)gh < (unsigned)Hn && (unsigned)gw < (unsigned)Wn) {
      const float* lp = lg0 + gh * Wn + gw;
      float v[NCn];
      float m = -1e30f;
      #pragma unroll
      for (int o = 0; o < NCn; o++) { v[o] = lp[(size_t)o * HWSZ]; m = fmaxf(m, v[o]); }
      float s = 0.f;
      #pragma unroll
      for (int o = 0; o < NCn; o++) { v[o] = __expf(v[o] - m); s += v[o]; }
      float inv = 1.0f / s;
      #pragma unroll
      for (int o = 0; o < NCn; o++) {
        int pk = __builtin_amdgcn_cvt_pk_fp8_f32(v[o] * inv, 0.f, 0, false);
        qp[o * HH * QSTR] = (uint8_t)(pk & 0xff);
      }
    } else {
      #pragma unroll
      for (int o = 0; o < NCn; o++) qp[o * HH * QSTR] = 0;
    }
  }
  __syncthreads();

  // ---------------- main loop: 4 px per thread --------------------------------------
  const int ty = tid >> 4;       // tile row 0..15
  const int tg = tid & 15;       // x-group
  const int x  = tg << 2;        // first tile col of this thread's 4 px

  float acc[4][NCn];
  #pragma unroll
  for (int p = 0; p < 4; p++)
    #pragma unroll
    for (int o = 0; o < NCn; o++) acc[p][o] = 0.f;

  #pragma unroll 1
  for (int di = 0; di < 7; di++) {
    const int lhn = ty + di;     // neighbor halo row
    float dsum[4][7];
    #pragma unroll
    for (int p = 0; p < 4; p++)
      #pragma unroll
      for (int j = 0; j < 7; j++) dsum[p][j] = 0.f;

    #pragma unroll 2
    for (int c2 = 0; c2 < C2n; c2++) {
      const uint32_t* frow = fbuf + (c2 * HH + lhn) * FW + x;
      const uint32_t* fcen = fbuf + (c2 * HH + (ty + PADn)) * FW + x + PADn;
      uint32_t nw[10], cw[4];
      #pragma unroll
      for (int j = 0; j < 10; j++) nw[j] = frow[j];
      #pragma unroll
      for (int p = 0; p < 4; p++) cw[p] = fcen[p];
      #pragma unroll
      for (int p = 0; p < 4; p++) {
        h2 c = __builtin_bit_cast(h2, cw[p]);
        #pragma unroll
        for (int j = 0; j < 7; j++) {
          h2 n = __builtin_bit_cast(h2, nw[p + j]);
          h2 d = c - n;
#if __has_builtin(__builtin_amdgcn_fdot2)
          dsum[p][j] = __builtin_amdgcn_fdot2(d, d, dsum[p][j], false);
#else
          float d0 = (float)d[0], d1 = (float)d[1];
          dsum[p][j] += d0 * d0 + d1 * d1;
#endif
        }
      }
    }
    // kern = exp(-diff/32)  (weight & 1/7 folded into compat epilogue)
    #pragma unroll
    for (int p = 0; p < 4; p++)
      #pragma unroll
      for (int j = 0; j < 7; j++)
        dsum[p][j] = __expf(dsum[p][j] * -0.03125f);

    // accumulate Q
    #pragma unroll
    for (int o = 0; o < NCn; o++) {
      const uint32_t* qrow = (const uint32_t*)(qbuf + (o * HH + lhn) * QSTR + x);
      uint32_t q0 = qrow[0], q1 = qrow[1], q2 = qrow[2];
      float qv[10];
      qv[0] = __builtin_amdgcn_cvt_f32_fp8((int)q0, 0);
      qv[1] = __builtin_amdgcn_cvt_f32_fp8((int)q0, 1);
      qv[2] = __builtin_amdgcn_cvt_f32_fp8((int)q0, 2);
      qv[3] = __builtin_amdgcn_cvt_f32_fp8((int)q0, 3);
      qv[4] = __builtin_amdgcn_cvt_f32_fp8((int)q1, 0);
      qv[5] = __builtin_amdgcn_cvt_f32_fp8((int)q1, 1);
      qv[6] = __builtin_amdgcn_cvt_f32_fp8((int)q1, 2);
      qv[7] = __builtin_amdgcn_cvt_f32_fp8((int)q1, 3);
      qv[8] = __builtin_amdgcn_cvt_f32_fp8((int)q2, 0);
      qv[9] = __builtin_amdgcn_cvt_f32_fp8((int)q2, 1);
      #pragma unroll
      for (int p = 0; p < 4; p++)
        #pragma unroll
        for (int j = 0; j < 7; j++)
          acc[p][o] = fmaf(dsum[p][j], qv[p + j], acc[p][o]);
    }
  }

  // ---------------- epilogue: compat mix + bias + logit subtract --------------------
  __syncthreads();
  float* cmat = (float*)(smem + LDS_Q_OFF);   // reuse Q area: 441 floats
  {
    float wgt = weight[0] * (1.0f / 7.0f);
    for (int i = tid; i < NCn * NCn; i += 256) {
      float c = compat[i];
      cmat[i] = wgt / (1.f + __expf(-c));     // sigmoid(c) * weight / 7
    }
  }
  __syncthreads();

  const int gh = h0 + ty;
  const size_t pixoff = (size_t)b * NCn * HWSZ + (size_t)gh * Wn + (w0 + x);
  const float* lc = logit + pixoff;
  float* oc = out + pixoff;
  #pragma unroll
  for (int o = 0; o < NCn; o++) {
    float s0 = 0.f, s1 = 0.f, s2 = 0.f, s3 = 0.f;
    #pragma unroll
    for (int i2 = 0; i2 < NCn; i2++) {
      float cm = cmat[o * NCn + i2];
      s0 = fmaf(cm, acc[0][i2], s0);
      s1 = fmaf(cm, acc[1][i2], s1);
      s2 = fmaf(cm, acc[2][i2], s2);
      s3 = fmaf(cm, acc[3][i2], s3);
    }
    float bo = bias[o];
    const float4 lg = *(const float4*)(lc + (size_t)o * HWSZ);
    float4 rr;
    rr.x = lg.x - s0 - bo;
    rr.y = lg.y - s1 - bo;
    rr.z = lg.z - s2 - bo;
    rr.w = lg.w - s3 - bo;
    *(float4*)(oc + (size_t)o * HWSZ) = rr;
  }
}

extern "C" void kernel_launch(void* const* d_in, const int* in_sizes, int n_in,
                              void* d_out, int out_size, void* d_ws, size_t ws_size,
                              hipStream_t stream) {
  (void)in_sizes; (void)n_in; (void)out_size; (void)d_ws; (void)ws_size;
  const float* F      = (const float*)d_in[0];
  const float* logit  = (const float*)d_in[1];
  const float* weight = (const float*)d_in[2];
  const float* compat = (const float*)d_in[3];
  const float* bias   = (const float*)d_in[4];
  float* out = (float*)d_out;

  hipFuncSetAttribute((const void*)crf_fused,
                      hipFuncAttributeMaxDynamicSharedMemorySize, LDS_TOTAL);
  crf_fused<<<dim3(Bn * 100), dim3(256), LDS_TOTAL, stream>>>(
      F, logit, weight, compat, bias, out);
}

// Round 5
// 250.660 us; speedup vs baseline: 1.1322x; 1.1322x over previous
//
#include <hip/hip_runtime.h>

#define Bn 4
#define Cn 32
#define Hn 320
#define Wn 320
#define NCn 21
#define HWSZ (Hn*Wn)

#define THr 32             // tile rows
#define TWr 64             // tile cols
#define HHr 38             // THr+6 halo rows
#define HWIDr 70           // TWr+6 valid halo cols
#define FWr 72             // F row stride in words (mult of 4 -> aligned b128)
#define NG 8               // 8 groups of 4 fp8 channels per 32-bit word
#define QSTRr 76           // Q row stride bytes (mult of 4)

typedef _Float16 h2 __attribute__((ext_vector_type(2)));

#define LDS_F   (NG*HHr*FWr*4)                 // 87552 B
#define LDS_Q   (NCn*HHr*QSTRr)                // 60648 B
#define LDS_TOTAL (LDS_F + LDS_Q)              // 148200 B

// exact fp8(e4m3) pair -> f16 pair scaled by 2^-8 (handles denormals exactly)
__device__ __forceinline__ h2 fp8pair_lo(uint32_t w) {
  uint32_t t = ((w & 0x000000FFu) << 8) | ((w & 0x0000FF00u) << 16); // {b0<<8, b1<<8}
  uint32_t r = (t & 0x80008000u) | ((t >> 1) & 0x3FFF3FFFu);
  return __builtin_bit_cast(h2, r);
}
__device__ __forceinline__ h2 fp8pair_hi(uint32_t w) {
  uint32_t t = ((w >> 8) & 0x0000FF00u) | (w & 0xFF000000u);         // {b2<<8, b3<<8}
  uint32_t r = (t & 0x80008000u) | ((t >> 1) & 0x3FFF3FFFu);
  return __builtin_bit_cast(h2, r);
}

__device__ __forceinline__ float fdot2f(h2 a, h2 b, float c) {
#if __has_builtin(__builtin_amdgcn_fdot2)
  return __builtin_amdgcn_fdot2(a, b, c, false);
#else
  return c + (float)a[0]*(float)b[0] + (float)a[1]*(float)b[1];
#endif
}

__global__ __launch_bounds__(512, 1) void crf_fused2(
    const float* __restrict__ Fin, const float* __restrict__ logit,
    const float* __restrict__ weight, const float* __restrict__ compat,
    const float* __restrict__ bias, float* __restrict__ out)
{
  extern __shared__ char smem[];
  uint32_t* fbuf = (uint32_t*)smem;                // [NG][HHr][FWr] fp8x4 words
  uint8_t*  qbuf = (uint8_t*)(smem + LDS_F);       // [NCn][HHr][QSTRr] fp8

  const int bid = blockIdx.x;
  const int b   = bid / 50;
  const int r   = bid % 50;
  const int th  = r / 5, twi = r % 5;
  const int h0  = th * THr, w0 = twi * TWr;
  const int tid = threadIdx.x;

  // ---------------- stage F: fp32 -> fp8x4 words --------------------------------
  const float* fb0 = Fin + (size_t)b * Cn * HWSZ;
  for (int idx = tid; idx < NG * HHr * FWr; idx += 512) {
    int lw = idx % FWr;
    int r2 = idx / FWr;
    int lh = r2 % HHr;
    int g  = r2 / HHr;
    int gh = h0 - 3 + lh, gw = w0 - 3 + lw;
    uint32_t wd = 0u;
    if (lw < HWIDr && (unsigned)gh < (unsigned)Hn && (unsigned)gw < (unsigned)Wn) {
      const float* p = fb0 + (size_t)(4 * g) * HWSZ + gh * Wn + gw;
      float f0 = p[0], f1 = p[HWSZ], f2 = p[2 * HWSZ], f3 = p[3 * HWSZ];
      int pk = __builtin_amdgcn_cvt_pk_fp8_f32(f0, f1, 0, false);
      pk = __builtin_amdgcn_cvt_pk_fp8_f32(f2, f3, pk, true);
      wd = (uint32_t)pk;
    }
    fbuf[idx] = wd;
  }

  // ---------------- stage Q = softmax(logit) as fp8 ------------------------------
  const float* lg0 = logit + (size_t)b * NCn * HWSZ;
  for (int p = tid; p < HHr * HWIDr; p += 512) {
    int lw = p % HWIDr, lh = p / HWIDr;
    int gh = h0 - 3 + lh, gw = w0 - 3 + lw;
    uint8_t* qp = qbuf + lh * QSTRr + lw;
    if ((unsigned)gh < (unsigned)Hn && (unsigned)gw < (unsigned)Wn) {
      const float* lp = lg0 + gh * Wn + gw;
      float v[NCn];
      float m = -1e30f;
      #pragma unroll
      for (int o = 0; o < NCn; o++) { v[o] = lp[(size_t)o * HWSZ]; m = fmaxf(m, v[o]); }
      float s = 0.f;
      #pragma unroll
      for (int o = 0; o < NCn; o++) { v[o] = __expf(v[o] - m); s += v[o]; }
      float inv = 1.0f / s;
      #pragma unroll
      for (int o = 0; o < NCn; o++) {
        int pk = __builtin_amdgcn_cvt_pk_fp8_f32(v[o] * inv, 0.f, 0, false);
        qp[(size_t)o * HHr * QSTRr] = (uint8_t)(pk & 0xff);
      }
    } else {
      #pragma unroll
      for (int o = 0; o < NCn; o++) qp[(size_t)o * HHr * QSTRr] = 0;
    }
  }
  __syncthreads();

  // ---------------- main: 4 px/thread, 32 rows x 16 col-groups -------------------
  const int ty = tid >> 4;       // 0..31 tile row
  const int tg = tid & 15;       // x-group
  const int x  = tg << 2;        // first of 4 px (16B-aligned word offset)

  // hoist centers: [g][2p]=ch(4g..4g+1), [g][2p+1]=ch(4g+2..4g+3), f16*2^-8
  h2 cen[NG][8];
  #pragma unroll
  for (int g = 0; g < NG; g++) {
    const uint32_t* fc = fbuf + (g * HHr + (ty + 3)) * FWr + (x + 3);
    #pragma unroll
    for (int p = 0; p < 4; p++) {
      uint32_t w = fc[p];
      cen[g][2 * p]     = fp8pair_lo(w);
      cen[g][2 * p + 1] = fp8pair_hi(w);
    }
  }

  float acc[4][NCn];
  #pragma unroll
  for (int p = 0; p < 4; p++)
    #pragma unroll
    for (int o = 0; o < NCn; o++) acc[p][o] = 0.f;

  #pragma unroll 1
  for (int di = 0; di < 7; di++) {
    const int lhn = ty + di;
    float ds[4][7];
    #pragma unroll
    for (int p = 0; p < 4; p++)
      #pragma unroll
      for (int j = 0; j < 7; j++) ds[p][j] = 0.f;

    #pragma unroll
    for (int g = 0; g < NG; g++) {
      const uint32_t* frow = fbuf + (g * HHr + lhn) * FWr + x;
      uint4 n0 = *(const uint4*)(frow);
      uint4 n1 = *(const uint4*)(frow + 4);
      uint4 n2 = *(const uint4*)(frow + 8);
      uint32_t nw[10] = {n0.x, n0.y, n0.z, n0.w, n1.x, n1.y, n1.z, n1.w, n2.x, n2.y};
      #pragma unroll
      for (int k = 0; k < 10; k++) {
        h2 lo = fp8pair_lo(nw[k]);
        h2 hi = fp8pair_hi(nw[k]);
        #pragma unroll
        for (int p = 0; p < 4; p++) {
          const int j = k - p;
          if (j >= 0 && j < 7) {
            h2 d0 = cen[g][2 * p] - lo;
            h2 d1 = cen[g][2 * p + 1] - hi;
            float t = fdot2f(d0, d0, ds[p][j]);
            ds[p][j] = fdot2f(d1, d1, t);
          }
        }
      }
    }

    // kern = exp(-diff/C); ds carries 2^-16 scale -> multiplier -2048 = -(2^16/32)
    float kern[4][7];
    #pragma unroll
    for (int p = 0; p < 4; p++)
      #pragma unroll
      for (int j = 0; j < 7; j++)
        kern[p][j] = __expf(ds[p][j] * -2048.0f);

    #pragma unroll
    for (int o = 0; o < NCn; o++) {
      const uint32_t* qrow = (const uint32_t*)(qbuf + (o * HHr + lhn) * QSTRr + x);
      uint32_t q0 = qrow[0], q1 = qrow[1], q2 = qrow[2];
      float qv[10];
      qv[0] = __builtin_amdgcn_cvt_f32_fp8((int)q0, 0);
      qv[1] = __builtin_amdgcn_cvt_f32_fp8((int)q0, 1);
      qv[2] = __builtin_amdgcn_cvt_f32_fp8((int)q0, 2);
      qv[3] = __builtin_amdgcn_cvt_f32_fp8((int)q0, 3);
      qv[4] = __builtin_amdgcn_cvt_f32_fp8((int)q1, 0);
      qv[5] = __builtin_amdgcn_cvt_f32_fp8((int)q1, 1);
      qv[6] = __builtin_amdgcn_cvt_f32_fp8((int)q1, 2);
      qv[7] = __builtin_amdgcn_cvt_f32_fp8((int)q1, 3);
      qv[8] = __builtin_amdgcn_cvt_f32_fp8((int)q2, 0);
      qv[9] = __builtin_amdgcn_cvt_f32_fp8((int)q2, 1);
      #pragma unroll
      for (int p = 0; p < 4; p++)
        #pragma unroll
        for (int j = 0; j < 7; j++)
          acc[p][o] = fmaf(kern[p][j], qv[p + j], acc[p][o]);
    }
  }

  // ---------------- epilogue: compat mix + bias + logit subtract -----------------
  __syncthreads();
  float* cmat = (float*)(smem + LDS_F);   // reuse Q area: 441 floats
  {
    float wgt = weight[0] * (1.0f / 7.0f);
    for (int i = tid; i < NCn * NCn; i += 512) {
      float c = compat[i];
      cmat[i] = wgt / (1.f + __expf(-c));  // sigmoid * weight / kernel_len
    }
  }
  __syncthreads();

  const int gh = h0 + ty;
  const size_t pixoff = (size_t)b * NCn * HWSZ + (size_t)gh * Wn + (w0 + x);
  const float* lc = logit + pixoff;
  float* oc = out + pixoff;
  #pragma unroll
  for (int o = 0; o < NCn; o++) {
    float s0 = 0.f, s1 = 0.f, s2 = 0.f, s3 = 0.f;
    #pragma unroll
    for (int i2 = 0; i2 < NCn; i2++) {
      float cm = cmat[o * NCn + i2];
      s0 = fmaf(cm, acc[0][i2], s0);
      s1 = fmaf(cm, acc[1][i2], s1);
      s2 = fmaf(cm, acc[2][i2], s2);
      s3 = fmaf(cm, acc[3][i2], s3);
    }
    float bo = bias[o];
    const float4 lg = *(const float4*)(lc + (size_t)o * HWSZ);
    float4 rr;
    rr.x = lg.x - s0 - bo;
    rr.y = lg.y - s1 - bo;
    rr.z = lg.z - s2 - bo;
    rr.w = lg.w - s3 - bo;
    *(float4*)(oc + (size_t)o * HWSZ) = rr;
  }
}

extern "C" void kernel_launch(void* const* d_in, const int* in_sizes, int n_in,
                              void* d_out, int out_size, void* d_ws, size_t ws_size,
                              hipStream_t stream) {
  (void)in_sizes; (void)n_in; (void)out_size; (void)d_ws; (void)ws_size;
  const float* F      = (const float*)d_in[0];
  const float* logit  = (const float*)d_in[1];
  const float* weight = (const float*)d_in[2];
  const float* compat = (const float*)d_in[3];
  const float* bias   = (const float*)d_in[4];
  float* out = (float*)d_out;

  hipFuncSetAttribute((const void*)crf_fused2,
                      hipFuncAttributeMaxDynamicSharedMemorySize, LDS_TOTAL);
  crf_fused2<<<dim3(Bn * 50), dim3(512), LDS_TOTAL, stream>>>(
      F, logit, weight, compat, bias, out);
}